// Round 1
// baseline (10109.263 us; speedup 1.0000x reference)
//
#include <hip/hip_runtime.h>
#include <math.h>

// Problem constants
#define Bb   4
#define Cc   128
#define Nn   4096          // 64*64 spatial
#define HP   0.1f
#define EPSN 1e-10f
#define EPSM 0.001f

// GEMM tiling
#define MSPLIT 8           // split of the m dimension across blocks
#define TILE   128         // n-rows and m-cols per block tile
#define KC     32          // K chunk staged in LDS
#define SS     36          // LDS row stride in floats (granule stride 9, odd -> conflict-free)
#define MT_PER_WG ((Nn / TILE) / MSPLIT)   // m-tiles per workgroup = 4

// Workspace layout (float offsets)
#define OFF_MEAN 0                         // [B*C]        = 512   (atomicAdd -> zeroed)
#define OFF_SSUM 512                       // [B*N]        = 16384 (atomicAdd -> zeroed)
#define OFF_DMIN (512 + 16384)             // [B*N]
#define OFF_T    (512 + 2 * 16384)         // [B*N]
#define OFF_PMAX (512 + 3 * 16384)         // [B*N*MSPLIT] = 131072
#define OFF_FXN  (512 + 3 * 16384 + Bb * Nn * MSPLIT)
#define OFF_FYN  (OFF_FXN + Bb * Nn * Cc)

// ---------------------------------------------------------------------------
// Kernel 1: per-(b,c) sums of feature_y over spatial dim (atomicAdd partials)
__global__ void k_mean(const float* __restrict__ fy, float* __restrict__ mean)
{
    int b = blockIdx.x >> 5;       // 32 chunks per batch
    int chunk = blockIdx.x & 31;
    int c = threadIdx.x;           // 128 threads, one per channel
    const float* p = fy + ((size_t)b * Nn + (size_t)chunk * 128) * Cc + c;
    float s = 0.f;
    for (int n = 0; n < 128; ++n) s += p[(size_t)n * Cc];
    atomicAdd(&mean[b * Cc + c], s);
}

// ---------------------------------------------------------------------------
// Kernel 2: center by mean_y, L2-normalize each (b,n) channel vector.
// One wave (64 threads) per (b,n); lane handles channels l and l+64.
__global__ void k_norm(const float* __restrict__ fx, const float* __restrict__ fy,
                       const float* __restrict__ mean,
                       float* __restrict__ fxn, float* __restrict__ fyn)
{
    int bn = blockIdx.x;           // 0 .. B*N-1
    int b = bn >> 12;              // / 4096
    int l = threadIdx.x;           // 0..63
    const float* px = fx + (size_t)bn * Cc;
    const float* py = fy + (size_t)bn * Cc;
    const float* mp = mean + b * Cc;

    float m0 = mp[l]      * (1.f / Nn);
    float m1 = mp[l + 64] * (1.f / Nn);
    float x0 = px[l] - m0, x1 = px[l + 64] - m1;
    float y0 = py[l] - m0, y1 = py[l + 64] - m1;
    float sx = x0 * x0 + x1 * x1;
    float sy = y0 * y0 + y1 * y1;
    #pragma unroll
    for (int o = 32; o > 0; o >>= 1) {
        sx += __shfl_xor(sx, o);
        sy += __shfl_xor(sy, o);
    }
    float ix = 1.f / (sqrtf(sx) + EPSN);
    float iy = 1.f / (sqrtf(sy) + EPSN);
    fxn[(size_t)bn * Cc + l]      = x0 * ix;
    fxn[(size_t)bn * Cc + l + 64] = x1 * ix;
    fyn[(size_t)bn * Cc + l]      = y0 * iy;
    fyn[(size_t)bn * Cc + l + 64] = y1 * iy;
}

// ---------------------------------------------------------------------------
// GEMM-like core. PASS 1: per-row running max of dot (-> pmax partials).
// PASS 2: recompute dots, accumulate s = sum_m exp((dmin - d)*t) (-> ssum atomics).
// Block: 256 threads = 16x16 grid; 128x128 tile; 8x8 microtile (rows ty+16j, cols tx+16i).
template <int PASS>
__global__ __launch_bounds__(256, 2) void k_gemm(
    const float* __restrict__ fxn, const float* __restrict__ fyn,
    float* __restrict__ pmax, const float* __restrict__ dmin,
    const float* __restrict__ tv, float* __restrict__ ssum)
{
    __shared__ float sfx[TILE * SS];
    __shared__ float sfy[TILE * SS];
    const int tid = threadIdx.x;
    const int tx = tid & 15, ty = tid >> 4;
    const int n0 = blockIdx.x * TILE;
    const int mz = blockIdx.y;
    const int b  = blockIdx.z;
    const float* fxb = fxn + (size_t)b * Nn * Cc;
    const float* fyb = fyn + (size_t)b * Nn * Cc;

    float rmax[8], dm[8], tt[8], ss[8];
    if (PASS == 1) {
        #pragma unroll
        for (int j = 0; j < 8; ++j) rmax[j] = -1e30f;
    } else {
        #pragma unroll
        for (int j = 0; j < 8; ++j) {
            int row = n0 + ty + 16 * j;
            dm[j] = dmin[b * Nn + row];
            tt[j] = tv[b * Nn + row];
            ss[j] = 0.f;
        }
    }

    for (int mt = 0; mt < MT_PER_WG; ++mt) {
        const int m0 = (mz * MT_PER_WG + mt) * TILE;
        float acc[8][8];
        #pragma unroll
        for (int j = 0; j < 8; ++j)
            #pragma unroll
            for (int i = 0; i < 8; ++i) acc[j][i] = 0.f;

        for (int kc = 0; kc < Cc / KC; ++kc) {
            __syncthreads();
            // Stage TILE x KC chunks of fx and fy (coalesced float4 global reads).
            #pragma unroll
            for (int i = 0; i < 4; ++i) {
                int idx = tid + 256 * i;
                int r = idx >> 3, g = idx & 7;      // 8 granules (32 floats) per row
                *(float4*)&sfx[r * SS + 4 * g] =
                    *(const float4*)&fxb[(size_t)(n0 + r) * Cc + kc * KC + 4 * g];
                *(float4*)&sfy[r * SS + 4 * g] =
                    *(const float4*)&fyb[(size_t)(m0 + r) * Cc + kc * KC + 4 * g];
            }
            __syncthreads();
            #pragma unroll
            for (int k4 = 0; k4 < KC / 4; ++k4) {
                float4 xa[8], yb[8];
                #pragma unroll
                for (int j = 0; j < 8; ++j)
                    xa[j] = *(const float4*)&sfx[(ty + 16 * j) * SS + 4 * k4];
                #pragma unroll
                for (int i = 0; i < 8; ++i)
                    yb[i] = *(const float4*)&sfy[(tx + 16 * i) * SS + 4 * k4];
                #pragma unroll
                for (int j = 0; j < 8; ++j)
                    #pragma unroll
                    for (int i = 0; i < 8; ++i)
                        acc[j][i] += xa[j].x * yb[i].x + xa[j].y * yb[i].y
                                   + xa[j].z * yb[i].z + xa[j].w * yb[i].w;
            }
        }

        if (PASS == 1) {
            #pragma unroll
            for (int j = 0; j < 8; ++j) {
                float v = acc[j][0];
                #pragma unroll
                for (int i = 1; i < 8; ++i) v = fmaxf(v, acc[j][i]);
                rmax[j] = fmaxf(rmax[j], v);
            }
        } else {
            #pragma unroll
            for (int j = 0; j < 8; ++j) {
                float s = 0.f;
                #pragma unroll
                for (int i = 0; i < 8; ++i) {
                    float d = 1.f - acc[j][i];
                    s += __expf((dm[j] - d) * tt[j]);   // exponent <= 0, no overflow
                }
                ss[j] += s;
            }
        }
    }

    // Row r = n0 + ty + 16*j is owned by the 16 lanes sharing ty (contiguous in wave).
    if (PASS == 1) {
        #pragma unroll
        for (int j = 0; j < 8; ++j) {
            float v = rmax[j];
            #pragma unroll
            for (int o = 1; o < 16; o <<= 1) v = fmaxf(v, __shfl_xor(v, o));
            if (tx == 0)
                pmax[(size_t)(b * Nn + n0 + ty + 16 * j) * MSPLIT + mz] = v;
        }
    } else {
        #pragma unroll
        for (int j = 0; j < 8; ++j) {
            float v = ss[j];
            #pragma unroll
            for (int o = 1; o < 16; o <<= 1) v += __shfl_xor(v, o);
            if (tx == 0)
                atomicAdd(&ssum[b * Nn + n0 + ty + 16 * j], v);
        }
    }
}

// ---------------------------------------------------------------------------
// Kernel 3b: reduce max partials -> dmin and exponent scale t
__global__ void k_dmin(const float* __restrict__ pmax, float* __restrict__ dmin,
                       float* __restrict__ tv)
{
    int i = blockIdx.x * 256 + threadIdx.x;   // 0 .. B*N-1
    float v = -1e30f;
    #pragma unroll
    for (int z = 0; z < MSPLIT; ++z) v = fmaxf(v, pmax[(size_t)i * MSPLIT + z]);
    float d = 1.f - v;
    dmin[i] = d;
    tv[i] = 1.f / (HP * (d + EPSM));
}

// ---------------------------------------------------------------------------
// Kernel 5: out[b] = -log( mean_n 1/s[b,n] )
__global__ void k_final(const float* __restrict__ ssum, float* __restrict__ out)
{
    int b = blockIdx.x;
    int tid = threadIdx.x;   // 256
    float s = 0.f;
    for (int n = tid; n < Nn; n += 256) s += 1.f / ssum[b * Nn + n];
    #pragma unroll
    for (int o = 32; o > 0; o >>= 1) s += __shfl_xor(s, o);
    __shared__ float red[4];
    if ((tid & 63) == 0) red[tid >> 6] = s;
    __syncthreads();
    if (tid == 0) {
        float t = red[0] + red[1] + red[2] + red[3];
        out[b] = -logf(t * (1.f / Nn));
    }
}

// ---------------------------------------------------------------------------
extern "C" void kernel_launch(void* const* d_in, const int* in_sizes, int n_in,
                              void* d_out, int out_size, void* d_ws, size_t ws_size,
                              hipStream_t stream)
{
    const float* fx = (const float*)d_in[0];
    const float* fy = (const float*)d_in[1];
    float* out = (float*)d_out;
    float* ws  = (float*)d_ws;

    float* mean = ws + OFF_MEAN;
    float* ssum = ws + OFF_SSUM;
    float* dmin = ws + OFF_DMIN;
    float* tv   = ws + OFF_T;
    float* pmax = ws + OFF_PMAX;
    float* fxn  = ws + OFF_FXN;
    float* fyn  = ws + OFF_FYN;

    // zero the atomicAdd accumulators (mean + ssum are contiguous at ws start)
    hipMemsetAsync(d_ws, 0, (size_t)(512 + Bb * Nn) * sizeof(float), stream);

    k_mean<<<dim3(Bb * 32), dim3(128), 0, stream>>>(fy, mean);
    k_norm<<<dim3(Bb * Nn), dim3(64), 0, stream>>>(fx, fy, mean, fxn, fyn);

    dim3 gg(Nn / TILE, MSPLIT, Bb);   // (32, 8, 4)
    k_gemm<1><<<gg, dim3(256), 0, stream>>>(fxn, fyn, pmax, nullptr, nullptr, nullptr);
    k_dmin<<<dim3(Bb * Nn / 256), dim3(256), 0, stream>>>(pmax, dmin, tv);
    k_gemm<2><<<gg, dim3(256), 0, stream>>>(fxn, fyn, nullptr, dmin, tv, ssum);
    k_final<<<dim3(Bb), dim3(256), 0, stream>>>(ssum, out);
}

// Round 2
// 185.376 us; speedup vs baseline: 54.5338x; 54.5338x over previous
//
#include <hip/hip_runtime.h>
#include <hip/hip_bf16.h>
#include <math.h>

// Problem constants
#define Bb   4
#define Cc   128
#define Nn   4096          // 64*64 spatial
#define HP   0.1f
#define EPSN 1e-10f
#define EPSM 0.001f

#define LS   136           // LDS row stride in bf16 (128 + 8 pad -> bank-uniform)

typedef __attribute__((ext_vector_type(8))) short short8;  // 8 bf16 = 4 VGPRs
typedef __attribute__((ext_vector_type(4))) float f32x4;   // MFMA accumulator

// Workspace layout (float offsets; all multiples of 8 -> 16B aligned)
#define OFF_MEAN 0                 // [B*C]      = 512      (atomicAdd -> zeroed)
#define OFF_DMIN 512               // [B*N]      = 16384
#define OFF_TV   16896             // [B*N]      = 16384
#define OFF_PMAX 33280             // [B*N*32]   = 524288   (fully overwritten)
#define OFF_SSP  557568            // [B*N*32]   = 524288   (fully overwritten)
#define OFF_FXN  1081856           // bf16 [B*N*C] = 2M elems = 1048576 floats
#define OFF_FYN  2130432           // bf16 [B*N*C]

// ---------------------------------------------------------------------------
// Kernel 1: per-(b,c) sums of feature_y over spatial dim (atomicAdd partials)
__global__ void k_mean(const float* __restrict__ fy, float* __restrict__ mean)
{
    int b = blockIdx.x >> 5;
    int chunk = blockIdx.x & 31;
    int c = threadIdx.x;           // 128 threads, one per channel
    const float* p = fy + ((size_t)b * Nn + (size_t)chunk * 128) * Cc + c;
    float s = 0.f;
    for (int n = 0; n < 128; ++n) s += p[(size_t)n * Cc];
    atomicAdd(&mean[b * Cc + c], s);
}

// ---------------------------------------------------------------------------
// Kernel 2: center by spatial mean of y, L2-normalize each (b,n) vector over C,
// emit bf16. One wave per (b,n); lane handles channels l and l+64.
__global__ void k_norm(const float* __restrict__ fx, const float* __restrict__ fy,
                       const float* __restrict__ mean,
                       __hip_bfloat16* __restrict__ fxn, __hip_bfloat16* __restrict__ fyn)
{
    int bn = blockIdx.x;           // 0 .. B*N-1
    int b = bn >> 12;
    int l = threadIdx.x;           // 0..63
    const float* px = fx + (size_t)bn * Cc;
    const float* py = fy + (size_t)bn * Cc;
    const float* mp = mean + b * Cc;

    float m0 = mp[l]      * (1.f / Nn);
    float m1 = mp[l + 64] * (1.f / Nn);
    float x0 = px[l] - m0, x1 = px[l + 64] - m1;
    float y0 = py[l] - m0, y1 = py[l + 64] - m1;
    float sx = x0 * x0 + x1 * x1;
    float sy = y0 * y0 + y1 * y1;
    #pragma unroll
    for (int o = 32; o > 0; o >>= 1) {
        sx += __shfl_xor(sx, o);
        sy += __shfl_xor(sy, o);
    }
    float ix = 1.f / (sqrtf(sx) + EPSN);
    float iy = 1.f / (sqrtf(sy) + EPSN);
    fxn[(size_t)bn * Cc + l]      = __float2bfloat16(x0 * ix);
    fxn[(size_t)bn * Cc + l + 64] = __float2bfloat16(x1 * ix);
    fyn[(size_t)bn * Cc + l]      = __float2bfloat16(y0 * iy);
    fyn[(size_t)bn * Cc + l + 64] = __float2bfloat16(y1 * iy);
}

// ---------------------------------------------------------------------------
// MFMA core: per batch, S = X · Y^T  (M=N=4096, K=C=128), 128x128 tile/block,
// 4 waves in 2x2; each wave does a 64x64 subtile = 4x4 mfma_f32_16x16x32_bf16.
// PASS 1: per-row max of dot -> pmax[(b*N+row)*32 + mtile]
// PASS 2: per-row sum of exp((dmin-d)*t) -> ssp[(b*N+row)*32 + mtile]
template <int PASS>
__global__ __launch_bounds__(256, 2) void k_gemm(
    const ushort* __restrict__ fxn, const ushort* __restrict__ fyn,
    float* __restrict__ pmax, const float* __restrict__ dmin,
    const float* __restrict__ tv, float* __restrict__ ssp)
{
    __shared__ ushort sA[128 * LS];
    __shared__ ushort sB[128 * LS];
    __shared__ float  sred[128 * 2];
    __shared__ float  sdm[128];
    __shared__ float  stv[128];

    const int tid = threadIdx.x;
    const int n0 = blockIdx.x * 128;
    const int my = blockIdx.y;
    const int m0 = my * 128;
    const int b  = blockIdx.z;

    if (PASS == 2 && tid < 128) {
        sdm[tid] = dmin[b * Nn + n0 + tid];
        stv[tid] = tv[b * Nn + n0 + tid];
    }

    // Stage both 128x128 bf16 tiles (16B per thread-chunk, fully coalesced).
    {
        const float4* gA = (const float4*)(fxn + (size_t)b * Nn * Cc);
        const float4* gB = (const float4*)(fyn + (size_t)b * Nn * Cc);
        #pragma unroll
        for (int it = 0; it < 8; ++it) {
            int cid = tid + 256 * it;          // 0..2047
            int row = cid >> 4, c16 = cid & 15; // 16 x 16B chunks per 128-bf16 row
            *(float4*)&sA[row * LS + c16 * 8] = gA[((size_t)(n0 + row) << 4) + c16];
            *(float4*)&sB[row * LS + c16 * 8] = gB[((size_t)(m0 + row) << 4) + c16];
        }
    }
    __syncthreads();

    const int lane = tid & 63;
    const int w  = tid >> 6;
    const int wy = w >> 1, wx = w & 1;       // wave's 64x64 quadrant
    const int l15 = lane & 15, q = lane >> 4;

    f32x4 acc[4][4];
    #pragma unroll
    for (int i = 0; i < 4; ++i)
        #pragma unroll
        for (int j = 0; j < 4; ++j)
            acc[i][j] = (f32x4){0.f, 0.f, 0.f, 0.f};

    #pragma unroll
    for (int kt = 0; kt < 4; ++kt) {          // K chunks of 32
        short8 a[4], bb[4];
        const int ko = kt * 32 + q * 8;
        #pragma unroll
        for (int i = 0; i < 4; ++i)
            a[i] = *(const short8*)&sA[(wy * 64 + i * 16 + l15) * LS + ko];
        #pragma unroll
        for (int j = 0; j < 4; ++j)
            bb[j] = *(const short8*)&sB[(wx * 64 + j * 16 + l15) * LS + ko];
        #pragma unroll
        for (int i = 0; i < 4; ++i)
            #pragma unroll
            for (int j = 0; j < 4; ++j)
                acc[i][j] = __builtin_amdgcn_mfma_f32_16x16x32_bf16(
                    a[i], bb[j], acc[i][j], 0, 0, 0);
    }

    // C/D layout: col = lane&15, row = (lane>>4)*4 + reg  [m89-verified]
    // Lane's element (i,j,r): S row = n0+wy*64+i*16+q*4+r, col = m0+wx*64+j*16+l15.
    if (PASS == 1) {
        #pragma unroll
        for (int i = 0; i < 4; ++i)
            #pragma unroll
            for (int r = 0; r < 4; ++r) {
                float v = acc[i][0][r];
                #pragma unroll
                for (int j = 1; j < 4; ++j) v = fmaxf(v, acc[i][j][r]);
                #pragma unroll
                for (int o = 1; o < 16; o <<= 1) v = fmaxf(v, __shfl_xor(v, o));
                if (l15 == 0) sred[(wy * 64 + i * 16 + q * 4 + r) * 2 + wx] = v;
            }
        __syncthreads();
        if (tid < 128)
            pmax[((size_t)(b * Nn + n0 + tid) << 5) + my] =
                fmaxf(sred[tid * 2], sred[tid * 2 + 1]);
    } else {
        #pragma unroll
        for (int i = 0; i < 4; ++i) {
            const int rb = wy * 64 + i * 16 + q * 4;
            #pragma unroll
            for (int r = 0; r < 4; ++r) {
                // arg = (dmin - d)*t = (dmin - 1 + dot)*t = dot*c1 + c0  (<= ~0)
                float c1 = stv[rb + r];
                float c0 = (sdm[rb + r] - 1.f) * c1;
                float s = 0.f;
                #pragma unroll
                for (int j = 0; j < 4; ++j)
                    s += __expf(fmaf(acc[i][j][r], c1, c0));
                #pragma unroll
                for (int o = 1; o < 16; o <<= 1) s += __shfl_xor(s, o);
                if (l15 == 0) sred[(rb + r) * 2 + wx] = s;
            }
        }
        __syncthreads();
        if (tid < 128)
            ssp[((size_t)(b * Nn + n0 + tid) << 5) + my] =
                sred[tid * 2] + sred[tid * 2 + 1];
    }
}

// ---------------------------------------------------------------------------
// Reduce 32 max partials -> dmin and exponent scale t
__global__ void k_dmin(const float* __restrict__ pmax, float* __restrict__ dmin,
                       float* __restrict__ tv)
{
    int i = blockIdx.x * 256 + threadIdx.x;   // 0 .. B*N-1
    float g = -1e30f;
    #pragma unroll
    for (int z = 0; z < 32; ++z) g = fmaxf(g, pmax[((size_t)i << 5) + z]);
    float d = 1.f - g;
    dmin[i] = d;
    tv[i] = 1.f / (HP * (d + EPSM));
}

// ---------------------------------------------------------------------------
// out[b] = -log( mean_n 1 / (sum_mb ssp[b,n,mb]) )
__global__ void k_final(const float* __restrict__ ssp, float* __restrict__ out)
{
    int b = blockIdx.x;
    int tid = threadIdx.x;   // 256
    float s = 0.f;
    for (int n = tid; n < Nn; n += 256) {
        float t = 0.f;
        #pragma unroll
        for (int mb = 0; mb < 32; ++mb) t += ssp[((size_t)(b * Nn + n) << 5) + mb];
        s += 1.f / t;
    }
    #pragma unroll
    for (int o = 32; o > 0; o >>= 1) s += __shfl_xor(s, o);
    __shared__ float red[4];
    if ((tid & 63) == 0) red[tid >> 6] = s;
    __syncthreads();
    if (tid == 0) {
        float t = red[0] + red[1] + red[2] + red[3];
        out[b] = -logf(t * (1.f / Nn));
    }
}

// ---------------------------------------------------------------------------
extern "C" void kernel_launch(void* const* d_in, const int* in_sizes, int n_in,
                              void* d_out, int out_size, void* d_ws, size_t ws_size,
                              hipStream_t stream)
{
    const float* fx = (const float*)d_in[0];
    const float* fy = (const float*)d_in[1];
    float* out = (float*)d_out;
    float* ws  = (float*)d_ws;

    float* mean = ws + OFF_MEAN;
    float* dmin = ws + OFF_DMIN;
    float* tv   = ws + OFF_TV;
    float* pmax = ws + OFF_PMAX;
    float* ssp  = ws + OFF_SSP;
    __hip_bfloat16* fxn = (__hip_bfloat16*)(ws + OFF_FXN);
    __hip_bfloat16* fyn = (__hip_bfloat16*)(ws + OFF_FYN);

    // zero only the atomicAdd accumulator (mean)
    hipMemsetAsync(mean, 0, 512 * sizeof(float), stream);

    k_mean<<<dim3(Bb * 32), dim3(128), 0, stream>>>(fy, mean);
    k_norm<<<dim3(Bb * Nn), dim3(64), 0, stream>>>(fx, fy, mean, fxn, fyn);

    dim3 gg(32, 32, Bb);
    k_gemm<1><<<gg, dim3(256), 0, stream>>>((const ushort*)fxn, (const ushort*)fyn,
                                            pmax, nullptr, nullptr, nullptr);
    k_dmin<<<dim3(Bb * Nn / 256), dim3(256), 0, stream>>>(pmax, dmin, tv);
    k_gemm<2><<<gg, dim3(256), 0, stream>>>((const ushort*)fxn, (const ushort*)fyn,
                                            nullptr, dmin, tv, ssp);
    k_final<<<dim3(Bb), dim3(256), 0, stream>>>(ssp, out);
}

// Round 3
// 165.427 us; speedup vs baseline: 61.1103x; 1.1206x over previous
//
#include <hip/hip_runtime.h>
#include <hip/hip_bf16.h>
#include <math.h>

// Problem constants
#define Bb   4
#define Cc   128
#define Nn   4096          // 64*64 spatial
#define BN   (Bb * Nn)
#define HP   0.1f
#define EPSN 1e-10f
#define EPSM 0.001f

typedef __attribute__((ext_vector_type(8))) short short8;  // 8 bf16 = 4 VGPRs
typedef __attribute__((ext_vector_type(4))) float f32x4;   // MFMA accumulator

// Workspace layout (float offsets)
#define OFF_MEAN 0                 // [B*C]   = 512   (atomicAdd -> zeroed)
#define OFF_ACC  512               // [B]     = 4     (atomicAdd -> zeroed)
#define OFF_DMIN 1024              // [B*N]
#define OFF_TV   17408             // [B*N]
#define OFF_PMAX 33792             // [8][B*N] = 131072  (fully overwritten)
#define OFF_SSP  164864            // [8][B*N] = 131072  (fully overwritten)
#define OFF_FXN  295936            // bf16 [B*N*C] = 1048576 floats
#define OFF_FYN  1344512           // bf16 [B*N*C]

// async global -> LDS, 16B per lane; LDS dest = wave-uniform base + lane*16
__device__ __forceinline__ void gload_lds16(const void* g, void* l)
{
    __builtin_amdgcn_global_load_lds(
        (const __attribute__((address_space(1))) unsigned int*)g,
        (__attribute__((address_space(3))) unsigned int*)l, 16, 0, 0);
}

// ---------------------------------------------------------------------------
// Kernel 1: per-(b,c) sums of feature_y over spatial dim (atomicAdd partials)
__global__ void k_mean(const float* __restrict__ fy, float* __restrict__ mean)
{
    int b = blockIdx.x >> 5;
    int chunk = blockIdx.x & 31;
    int c = threadIdx.x;           // 128 threads, one per channel
    const float* p = fy + ((size_t)b * Nn + (size_t)chunk * 128) * Cc + c;
    float s = 0.f;
    for (int n = 0; n < 128; ++n) s += p[(size_t)n * Cc];
    atomicAdd(&mean[b * Cc + c], s);
}

// ---------------------------------------------------------------------------
// Kernel 2: center by spatial mean of y, L2-normalize each (b,n) vector over C,
// emit bf16. 256 threads = 4 waves, one wave per (b,n) row.
__global__ void k_norm(const float* __restrict__ fx, const float* __restrict__ fy,
                       const float* __restrict__ mean,
                       __hip_bfloat16* __restrict__ fxn, __hip_bfloat16* __restrict__ fyn)
{
    int bn = blockIdx.x * 4 + (threadIdx.x >> 6);   // 0 .. B*N-1
    int b = bn >> 12;
    int l = threadIdx.x & 63;
    const float* px = fx + (size_t)bn * Cc;
    const float* py = fy + (size_t)bn * Cc;
    const float* mp = mean + b * Cc;

    float m0 = mp[l]      * (1.f / Nn);
    float m1 = mp[l + 64] * (1.f / Nn);
    float x0 = px[l] - m0, x1 = px[l + 64] - m1;
    float y0 = py[l] - m0, y1 = py[l + 64] - m1;
    float sx = x0 * x0 + x1 * x1;
    float sy = y0 * y0 + y1 * y1;
    #pragma unroll
    for (int o = 32; o > 0; o >>= 1) {
        sx += __shfl_xor(sx, o);
        sy += __shfl_xor(sy, o);
    }
    float ix = 1.f / (sqrtf(sx) + EPSN);
    float iy = 1.f / (sqrtf(sy) + EPSN);
    fxn[(size_t)bn * Cc + l]      = __float2bfloat16(x0 * ix);
    fxn[(size_t)bn * Cc + l + 64] = __float2bfloat16(x1 * ix);
    fyn[(size_t)bn * Cc + l]      = __float2bfloat16(y0 * iy);
    fyn[(size_t)bn * Cc + l + 64] = __float2bfloat16(y1 * iy);
}

// ---------------------------------------------------------------------------
// MFMA core: per batch, S = X · Y^T  (M=N=4096, K=C=128).
// Block = 128-row strip tile of A (staged once) x 4 m-tiles of B (looped).
// LDS layout XOR-swizzled: chunk16 c of row r stored at slot c^(r&15)
// -> staging is lane-linear (global_load_lds ok), ds_read_b128 is 2-way (free).
// PASS 1: per-row running max of dot -> pmax[my][b*N+row]
// PASS 2: per-row running sum of exp((dmin-d)*t) -> ssp[my][b*N+row]
template <int PASS>
__global__ __launch_bounds__(256, 2) void k_gemm(
    const ushort* __restrict__ fxn, const ushort* __restrict__ fyn,
    float* __restrict__ pmax, const float* __restrict__ dmin,
    const float* __restrict__ tv, float* __restrict__ ssp)
{
    __shared__ ushort sA[128 * 128];
    __shared__ ushort sB[128 * 128];
    __shared__ float  sred[128 * 2];
    __shared__ float  sdm[128], stv[128];

    const int tid  = threadIdx.x;
    const int lane = tid & 63;
    const int w    = tid >> 6;
    const int n0   = blockIdx.x * 128;
    const int my   = blockIdx.y;          // 0..7 -> m-tiles my*4 .. my*4+3
    const int b    = blockIdx.z;

    const ushort* gA = fxn + (size_t)b * Nn * Cc;
    const ushort* gB = fyn + (size_t)b * Nn * Cc;

    if (PASS == 2 && tid < 128) {
        sdm[tid] = dmin[b * Nn + n0 + tid];
        stv[tid] = tv[b * Nn + n0 + tid];
    }

    // Stage A tile once: 2048 chunks16; wave w covers linear slots w*512 + inst*64 + lane.
    {
        #pragma unroll
        for (int inst = 0; inst < 8; ++inst) {
            int L0 = w * 512 + inst * 64;
            int L  = L0 + lane;
            int r = L >> 4, s = L & 15;
            int c = s ^ (r & 15);
            gload_lds16(gA + (size_t)(n0 + r) * Cc + c * 8, &sA[L0 * 8]);
        }
    }

    const int l15 = lane & 15, q = lane >> 4;
    const int wy = w >> 1, wx = w & 1;     // wave's 64x64 quadrant

    float rm[4][4];                         // PASS1: running max
    float sa[4][4];                         // PASS2: running exp-sum
    float dm[4][4], tt[4][4];
    #pragma unroll
    for (int i = 0; i < 4; ++i)
        #pragma unroll
        for (int r = 0; r < 4; ++r) { rm[i][r] = -1e30f; sa[i][r] = 0.f; }

    #pragma unroll
    for (int mt = 0; mt < 4; ++mt) {
        const int m0 = (my * 4 + mt) * 128;
        // Stage B tile for this m-tile.
        #pragma unroll
        for (int inst = 0; inst < 8; ++inst) {
            int L0 = w * 512 + inst * 64;
            int L  = L0 + lane;
            int r = L >> 4, s = L & 15;
            int c = s ^ (r & 15);
            gload_lds16(gB + (size_t)(m0 + r) * Cc + c * 8, &sB[L0 * 8]);
        }
        __syncthreads();   // drains vmcnt: A (first iter) + B staged, sdm/stv visible

        if (PASS == 2 && mt == 0) {
            #pragma unroll
            for (int i = 0; i < 4; ++i)
                #pragma unroll
                for (int r = 0; r < 4; ++r) {
                    int row = wy * 64 + i * 16 + q * 4 + r;
                    dm[i][r] = sdm[row];
                    tt[i][r] = stv[row];
                }
        }

        f32x4 acc[4][4];
        #pragma unroll
        for (int i = 0; i < 4; ++i)
            #pragma unroll
            for (int j = 0; j < 4; ++j)
                acc[i][j] = (f32x4){0.f, 0.f, 0.f, 0.f};

        #pragma unroll
        for (int kt = 0; kt < 4; ++kt) {
            short8 a[4], bb[4];
            const int sw = ((kt * 4 + q) ^ l15) * 8;   // swizzled chunk offset (ushorts)
            #pragma unroll
            for (int i = 0; i < 4; ++i)
                a[i] = *(const short8*)&sA[(wy * 64 + i * 16 + l15) * 128 + sw];
            #pragma unroll
            for (int j = 0; j < 4; ++j)
                bb[j] = *(const short8*)&sB[(wx * 64 + j * 16 + l15) * 128 + sw];
            #pragma unroll
            for (int i = 0; i < 4; ++i)
                #pragma unroll
                for (int j = 0; j < 4; ++j)
                    acc[i][j] = __builtin_amdgcn_mfma_f32_16x16x32_bf16(
                        a[i], bb[j], acc[i][j], 0, 0, 0);
        }

        // Fold this m-tile into running per-row state.
        // C/D layout: col = lane&15, row = (lane>>4)*4 + reg  [m89-verified]
        if (PASS == 1) {
            #pragma unroll
            for (int i = 0; i < 4; ++i)
                #pragma unroll
                for (int r = 0; r < 4; ++r) {
                    float v = acc[i][0][r];
                    #pragma unroll
                    for (int j = 1; j < 4; ++j) v = fmaxf(v, acc[i][j][r]);
                    rm[i][r] = fmaxf(rm[i][r], v);
                }
        } else {
            #pragma unroll
            for (int i = 0; i < 4; ++i)
                #pragma unroll
                for (int r = 0; r < 4; ++r) {
                    float c1 = tt[i][r];
                    float c0 = (dm[i][r] - 1.f) * c1;
                    float s = 0.f;
                    #pragma unroll
                    for (int j = 0; j < 4; ++j)
                        s += __expf(fmaf(acc[i][j][r], c1, c0));   // arg <= ~0
                    sa[i][r] += s;
                }
        }
        __syncthreads();   // all waves done reading sB before next staging
    }

    // Per-row reduction across the 16 columns (l15) and the wx wave pair.
    #pragma unroll
    for (int i = 0; i < 4; ++i)
        #pragma unroll
        for (int r = 0; r < 4; ++r) {
            float v = (PASS == 1) ? rm[i][r] : sa[i][r];
            if (PASS == 1) {
                #pragma unroll
                for (int o = 1; o < 16; o <<= 1) v = fmaxf(v, __shfl_xor(v, o));
            } else {
                #pragma unroll
                for (int o = 1; o < 16; o <<= 1) v += __shfl_xor(v, o);
            }
            if (l15 == 0) sred[(wy * 64 + i * 16 + q * 4 + r) * 2 + wx] = v;
        }
    __syncthreads();
    if (tid < 128) {
        if (PASS == 1)
            pmax[(size_t)my * BN + b * Nn + n0 + tid] =
                fmaxf(sred[tid * 2], sred[tid * 2 + 1]);
        else
            ssp[(size_t)my * BN + b * Nn + n0 + tid] =
                sred[tid * 2] + sred[tid * 2 + 1];
    }
}

// ---------------------------------------------------------------------------
// Reduce 8 max partials -> dmin and exponent scale t (coalesced reads)
__global__ void k_dmin(const float* __restrict__ pmax, float* __restrict__ dmin,
                       float* __restrict__ tv)
{
    int i = blockIdx.x * 256 + threadIdx.x;   // 0 .. B*N-1
    float g = -1e30f;
    #pragma unroll
    for (int z = 0; z < 8; ++z) g = fmaxf(g, pmax[(size_t)z * BN + i]);
    float d = 1.f - g;
    dmin[i] = d;
    tv[i] = 1.f / (HP * (d + EPSM));
}

// ---------------------------------------------------------------------------
// Stage 1 of final reduction: per-row 1/s, block-sum, atomicAdd per batch.
__global__ void k_partial(const float* __restrict__ ssp, float* __restrict__ acc)
{
    int i = blockIdx.x * 256 + threadIdx.x;   // 0 .. B*N-1 (block spans one batch)
    float t = 0.f;
    #pragma unroll
    for (int z = 0; z < 8; ++z) t += ssp[(size_t)z * BN + i];
    float s = 1.f / t;
    #pragma unroll
    for (int o = 32; o > 0; o >>= 1) s += __shfl_xor(s, o);
    __shared__ float red[4];
    if ((threadIdx.x & 63) == 0) red[threadIdx.x >> 6] = s;
    __syncthreads();
    if (threadIdx.x == 0)
        atomicAdd(&acc[i >> 12], red[0] + red[1] + red[2] + red[3]);
}

__global__ void k_out(const float* __restrict__ acc, float* __restrict__ out)
{
    int b = threadIdx.x;
    if (b < Bb) out[b] = -logf(acc[b] * (1.f / Nn));
}

// ---------------------------------------------------------------------------
extern "C" void kernel_launch(void* const* d_in, const int* in_sizes, int n_in,
                              void* d_out, int out_size, void* d_ws, size_t ws_size,
                              hipStream_t stream)
{
    const float* fx = (const float*)d_in[0];
    const float* fy = (const float*)d_in[1];
    float* out = (float*)d_out;
    float* ws  = (float*)d_ws;

    float* mean = ws + OFF_MEAN;
    float* acc  = ws + OFF_ACC;
    float* dmin = ws + OFF_DMIN;
    float* tv   = ws + OFF_TV;
    float* pmax = ws + OFF_PMAX;
    float* ssp  = ws + OFF_SSP;
    __hip_bfloat16* fxn = (__hip_bfloat16*)(ws + OFF_FXN);
    __hip_bfloat16* fyn = (__hip_bfloat16*)(ws + OFF_FYN);

    // zero the atomicAdd accumulators (mean @0..511, acc @512..515)
    hipMemsetAsync(ws, 0, 516 * sizeof(float), stream);

    k_mean<<<dim3(Bb * 32), dim3(128), 0, stream>>>(fy, mean);
    k_norm<<<dim3(Bb * Nn / 4), dim3(256), 0, stream>>>(fx, fy, mean, fxn, fyn);

    dim3 gg(32, 8, Bb);   // 1024 blocks, 2/CU
    k_gemm<1><<<gg, dim3(256), 0, stream>>>((const ushort*)fxn, (const ushort*)fyn,
                                            pmax, nullptr, nullptr, nullptr);
    k_dmin<<<dim3(BN / 256), dim3(256), 0, stream>>>(pmax, dmin, tv);
    k_gemm<2><<<gg, dim3(256), 0, stream>>>((const ushort*)fxn, (const ushort*)fyn,
                                            nullptr, dmin, tv, ssp);
    k_partial<<<dim3(BN / 256), dim3(256), 0, stream>>>(ssp, acc);
    k_out<<<dim3(1), dim3(64), 0, stream>>>(acc, out);
}